// Round 2
// baseline (6101.181 us; speedup 1.0000x reference)
//
#include <hip/hip_runtime.h>
#include <hip/hip_cooperative_groups.h>

#define T_LEN   128
#define BATCH   32
#define SZ      512
#define VOCAB_N 32000
#define GATE3   1536   // 3*SZ

typedef __attribute__((ext_vector_type(4))) float f32x4;
typedef __attribute__((ext_vector_type(8))) short bf16x8;
typedef __attribute__((ext_vector_type(4))) short s16x4;

// ---------------- device scratch (avoids ws_size assumptions) ----------------
__device__ short g_Wih_hi [GATE3 * SZ];
__device__ short g_Wih_lo [GATE3 * SZ];
__device__ short g_Wout_hi[VOCAB_N * SZ];
__device__ short g_Wout_lo[VOCAB_N * SZ];
__device__ short g_X_hi   [T_LEN * BATCH * SZ];
__device__ short g_X_lo   [T_LEN * BATCH * SZ];
__device__ short g_hs_hi  [T_LEN * BATCH * SZ];
__device__ short g_hs_lo  [T_LEN * BATCH * SZ];
__device__ float g_gi     [T_LEN * BATCH * GATE3];
__device__ float g_hA     [BATCH * SZ];
__device__ float g_hB     [BATCH * SZ];

// ---------------- bf16 split helpers (manual RNE) ----------------------------
__device__ __forceinline__ unsigned short f2bf(float x) {
  unsigned int u = __float_as_uint(x);
  u += 0x7fffu + ((u >> 16) & 1u);
  return (unsigned short)(u >> 16);
}
__device__ __forceinline__ float bf2f(unsigned short h) {
  return __uint_as_float(((unsigned int)h) << 16);
}

// ---------------- tiny kernels ----------------
__global__ void zero_weights(float* __restrict__ p) {
  int i = blockIdx.x * 256 + threadIdx.x;
  if (i < BATCH * 10 * 10) p[i] = 0.f;
}

// f32 -> (hi, lo) bf16 split, vectorized x4, grid-stride
__global__ void split_f32(const float* __restrict__ src, short* __restrict__ hi,
                          short* __restrict__ lo, int n4) {
  int i = blockIdx.x * blockDim.x + threadIdx.x;
  int stride = gridDim.x * blockDim.x;
  for (; i < n4; i += stride) {
    f32x4 v = ((const f32x4*)src)[i];
    s16x4 h, l;
#pragma unroll
    for (int j = 0; j < 4; ++j) {
      unsigned short hb = f2bf(v[j]);
      h[j] = (short)hb;
      l[j] = (short)f2bf(v[j] - bf2f(hb));
    }
    ((s16x4*)hi)[i] = h;
    ((s16x4*)lo)[i] = l;
  }
}

// gather emb rows per (t,b) and split to bf16 hi/lo; A-row r = t*32 + b
__global__ void gather_split(const int* __restrict__ inp, const float* __restrict__ emb) {
  int i = blockIdx.x * 256 + threadIdx.x;      // [0, 4096*128)
  if (i >= T_LEN * BATCH * (SZ / 4)) return;
  int r  = i >> 7;
  int c  = (i & 127) * 4;
  int t  = r >> 5, b = r & 31;
  long idx = inp[b * T_LEN + t];
  f32x4 v = *(const f32x4*)&emb[idx * SZ + c];
  s16x4 h, l;
#pragma unroll
  for (int j = 0; j < 4; ++j) {
    unsigned short hb = f2bf(v[j]);
    h[j] = (short)hb;
    l[j] = (short)f2bf(v[j] - bf2f(hb));
  }
  *(s16x4*)&g_X_hi[(long)r * SZ + c] = h;
  *(s16x4*)&g_X_lo[(long)r * SZ + c] = l;
}

// ---------------- split-bf16 3-term MFMA GEMM ----------------
// C[M, N] = A[M,512] * B[N,512]^T (+bias), via virtual K = 1536:
//   kt 0..7: Ahi*Bhi   kt 8..15: Ahi*Blo   kt 16..23: Alo*Bhi
typedef const __attribute__((address_space(1))) short* gas_p;
typedef __attribute__((address_space(3))) short*       las_p;

__device__ __forceinline__ void gll16(const short* g, short* l) {
  __builtin_amdgcn_global_load_lds((gas_p)g, (las_p)l, 16, 0, 0);
}

// MODE 0: C[m*1536 + n]                  (gi; bias = b_ih)
// MODE 1: C[(m&31)*T*V + (m>>5)*V + n]   (outputs; bias = b_out)
template <int MODE>
__global__ __launch_bounds__(256) void gemm3(
    const short* __restrict__ Ahi, const short* __restrict__ Alo,
    const short* __restrict__ Bhi, const short* __restrict__ Blo,
    const float* __restrict__ bias, float* __restrict__ C) {
  __shared__ __align__(16) short As[128 * 64];
  __shared__ __align__(16) short Bs[128 * 64];
  const int tid = threadIdx.x;

  // bijective XCD swizzle (nwg % 8 == 0 in both modes)
  const int nwg = gridDim.x * gridDim.y;
  const int wg  = blockIdx.y * gridDim.x + blockIdx.x;
  const int cpx = nwg >> 3;
  const int swz = (wg & 7) * cpx + (wg >> 3);
  const long tileN = (long)(swz % gridDim.x) * 128;
  const long tileM = (long)(swz / gridDim.x) * 128;

  const int wave = tid >> 6, lane = tid & 63;
  const int wm = (wave >> 1) * 64, wn = (wave & 1) * 64;
  const int lr = lane & 15, lk = lane >> 4;

  f32x4 acc[4][4] = {};

  for (int kt = 0; kt < 24; ++kt) {
    const int seg = kt >> 3;
    const int k0  = (kt & 7) * 64;
    const short* Asrc = (seg == 2) ? Alo : Ahi;
    const short* Bsrc = (seg == 1) ? Blo : Bhi;
#pragma unroll
    for (int i = 0; i < 4; ++i) {
      int elem = i * 2048 + tid * 8;         // lane-linear => valid lds dest
      int row  = elem >> 6, col = elem & 63;
      gll16(Asrc + (tileM + row) * SZ + k0 + col, As + elem);
      gll16(Bsrc + (tileN + row) * SZ + k0 + col, Bs + elem);
    }
    __syncthreads();
#pragma unroll
    for (int ks = 0; ks < 2; ++ks) {
      bf16x8 af[4], bfr[4];
#pragma unroll
      for (int f = 0; f < 4; ++f)
        af[f]  = *(const bf16x8*)&As[(wm + f * 16 + lr) * 64 + ks * 32 + lk * 8];
#pragma unroll
      for (int f = 0; f < 4; ++f)
        bfr[f] = *(const bf16x8*)&Bs[(wn + f * 16 + lr) * 64 + ks * 32 + lk * 8];
#pragma unroll
      for (int fm = 0; fm < 4; ++fm)
#pragma unroll
        for (int fn = 0; fn < 4; ++fn)
          acc[fm][fn] = __builtin_amdgcn_mfma_f32_16x16x32_bf16(
              af[fm], bfr[fn], acc[fm][fn], 0, 0, 0);
    }
    __syncthreads();
  }

#pragma unroll
  for (int fn = 0; fn < 4; ++fn) {
    const long n = tileN + wn + fn * 16 + lr;   // C/D: col = lane&15
    const float bi = bias[n];
#pragma unroll
    for (int fm = 0; fm < 4; ++fm) {
#pragma unroll
      for (int r = 0; r < 4; ++r) {
        const long m = tileM + wm + fm * 16 + lk * 4 + r;  // row=(lane>>4)*4+r
        float v = acc[fm][fn][r] + bi;
        if (MODE == 0)
          C[m * GATE3 + n] = v;
        else
          C[(m & 31) * (long)(T_LEN * VOCAB_N) + (m >> 5) * VOCAB_N + n] = v;
      }
    }
  }
}

// ---------------- GRU recurrence (cooperative, 1 grid.sync per step) --------
// 256 blocks x 256 thr; thread g = s*128 + b*4 + kg (kg = K-quarter of 128).
// Block covers 2 s-triples x 32 b x 4 kg. w_hh rows (12 KB) staged in LDS,
// skewed so the 4 kg-chunks hit disjoint banks (broadcast across 16 b-lanes).
#define WSTRIDE 528   // 512 + 16 floats: kg-chunk kg at offset kg*132
__global__ __launch_bounds__(256) void gru_kernel(const float* __restrict__ lh,
                                                  const float* __restrict__ whh,
                                                  const float* __restrict__ bhh) {
  cooperative_groups::grid_group grid = cooperative_groups::this_grid();
  __shared__ __align__(16) float wlds[6 * WSTRIDE];
  const int tid = threadIdx.x;
  const int g   = blockIdx.x * 256 + tid;
  const int kg  = g & 3;
  const int b   = (g >> 2) & 31;
  const int s   = g >> 7;                 // = blockIdx.x*2 + (tid>>7)
  const int s_local = tid >> 7;

  // stage 6 w_hh rows (2 s-triples) into skewed LDS
#pragma unroll
  for (int i = 0; i < 3; ++i) {
    int flat = i * 1024 + tid * 4;        // [0, 3072)
    int row  = flat >> 9;                 // 0..5 = s_local*3 + gate
    int k    = flat & 511;
    int sl   = row / 3, gate = row % 3;
    *(f32x4*)&wlds[row * WSTRIDE + (k >> 7) * 132 + (k & 127)] =
        *(const f32x4*)&whh[((long)gate * SZ + blockIdx.x * 2 + sl) * SZ + k];
  }

  // h0 = concat(lh[0], lh[1]) along features (blocks 0..63 participate)
  if (g < BATCH * SZ) {
    int bb = g >> 9, k = g & 511;
    g_hA[bb * SZ + k] = lh[(k >> 8) * (BATCH * 256) + bb * 256 + (k & 255)];
  }

  const float bhr = bhh[s];
  const float bhz = bhh[SZ + s];
  const float bhn = bhh[2 * SZ + s];
  const float* __restrict__ w_r = &wlds[(s_local * 3 + 0) * WSTRIDE + kg * 132];
  const float* __restrict__ w_z = &wlds[(s_local * 3 + 1) * WSTRIDE + kg * 132];
  const float* __restrict__ w_n = &wlds[(s_local * 3 + 2) * WSTRIDE + kg * 132];

  float* hcur = g_hA;
  float* hnxt = g_hB;
  __syncthreads();   // wlds ready
  grid.sync();       // h0 ready

  for (int t = 0; t < T_LEN; ++t) {
    const float* hb = hcur + b * SZ + kg * 128;
    float ar = 0.f, az = 0.f, an = 0.f;
#pragma unroll 8
    for (int j = 0; j < 32; ++j) {
      f32x4 h4 = *(const f32x4*)&hb[j * 4];
      f32x4 w4 = *(const f32x4*)&w_r[j * 4];
      ar += h4[0] * w4[0] + h4[1] * w4[1] + h4[2] * w4[2] + h4[3] * w4[3];
      w4 = *(const f32x4*)&w_z[j * 4];
      az += h4[0] * w4[0] + h4[1] * w4[1] + h4[2] * w4[2] + h4[3] * w4[3];
      w4 = *(const f32x4*)&w_n[j * 4];
      an += h4[0] * w4[0] + h4[1] * w4[1] + h4[2] * w4[2] + h4[3] * w4[3];
    }
    ar += __shfl_xor(ar, 1); ar += __shfl_xor(ar, 2);
    az += __shfl_xor(az, 1); az += __shfl_xor(az, 2);
    an += __shfl_xor(an, 1); an += __shfl_xor(an, 2);

    if (kg == 0) {
      const int row = t * BATCH + b;
      const float* gi = g_gi + (long)row * GATE3;
      float rg = 1.f / (1.f + __expf(-(gi[s] + ar + bhr)));
      float zg = 1.f / (1.f + __expf(-(gi[SZ + s] + az + bhz)));
      float ng = tanhf(gi[2 * SZ + s] + rg * (an + bhn));
      float ho = hcur[b * SZ + s];
      float hn = (1.f - zg) * ng + zg * ho;
      hnxt[b * SZ + s] = hn;
      unsigned short hh = f2bf(hn);
      g_hs_hi[(long)row * SZ + s] = (short)hh;
      g_hs_lo[(long)row * SZ + s] = (short)f2bf(hn - bf2f(hh));
    }
    float* tmp = hcur; hcur = hnxt; hnxt = tmp;
    grid.sync();
  }
}

// ---------------- host ----------------
extern "C" void kernel_launch(void* const* d_in, const int* in_sizes, int n_in,
                              void* d_out, int out_size, void* d_ws, size_t ws_size,
                              hipStream_t stream) {
  const int*   inp  = (const int*)  d_in[0];
  // d_in[1] = features: only shape matters; "weights" output is zeros
  const float* lh   = (const float*)d_in[2];
  const float* emb  = (const float*)d_in[3];
  const float* wih  = (const float*)d_in[4];
  const float* whh  = (const float*)d_in[5];
  const float* bih  = (const float*)d_in[6];
  const float* bhh  = (const float*)d_in[7];
  const float* wout = (const float*)d_in[8];
  const float* bout = (const float*)d_in[9];
  float* out  = (float*)d_out;
  float* outw = out + (long)BATCH * T_LEN * VOCAB_N;

  void *p_wih_hi, *p_wih_lo, *p_wout_hi, *p_wout_lo, *p_x_hi, *p_x_lo,
       *p_hs_hi, *p_hs_lo, *p_gi;
  hipGetSymbolAddress(&p_wih_hi,  HIP_SYMBOL(g_Wih_hi));
  hipGetSymbolAddress(&p_wih_lo,  HIP_SYMBOL(g_Wih_lo));
  hipGetSymbolAddress(&p_wout_hi, HIP_SYMBOL(g_Wout_hi));
  hipGetSymbolAddress(&p_wout_lo, HIP_SYMBOL(g_Wout_lo));
  hipGetSymbolAddress(&p_x_hi,    HIP_SYMBOL(g_X_hi));
  hipGetSymbolAddress(&p_x_lo,    HIP_SYMBOL(g_X_lo));
  hipGetSymbolAddress(&p_hs_hi,   HIP_SYMBOL(g_hs_hi));
  hipGetSymbolAddress(&p_hs_lo,   HIP_SYMBOL(g_hs_lo));
  hipGetSymbolAddress(&p_gi,      HIP_SYMBOL(g_gi));

  // independent prep
  zero_weights<<<13, 256, 0, stream>>>(outw);
  split_f32<<<768, 256, 0, stream>>>(wih,  (short*)p_wih_hi,  (short*)p_wih_lo,
                                     GATE3 * SZ / 4);
  split_f32<<<2048, 256, 0, stream>>>(wout, (short*)p_wout_hi, (short*)p_wout_lo,
                                      VOCAB_N * SZ / 4);
  gather_split<<<2048, 256, 0, stream>>>(inp, emb);

  // gi = X @ w_ih^T + b_ih   [4096, 1536]
  gemm3<0><<<dim3(GATE3 / 128, (T_LEN * BATCH) / 128), 256, 0, stream>>>(
      (const short*)p_x_hi, (const short*)p_x_lo,
      (const short*)p_wih_hi, (const short*)p_wih_lo, bih, (float*)p_gi);

  // GRU recurrence (cooperative, 128 grid syncs)
  {
    void* args[3] = {(void*)&lh, (void*)&whh, (void*)&bhh};
    hipLaunchCooperativeKernel((void*)gru_kernel, dim3(256), dim3(256), args, 0,
                               stream);
  }

  // outputs = hs @ w_out^T + b_out   -> [B, T, V] with row permutation
  gemm3<1><<<dim3(VOCAB_N / 128, (T_LEN * BATCH) / 128), 256, 0, stream>>>(
      (const short*)p_hs_hi, (const short*)p_hs_lo,
      (const short*)p_wout_hi, (const short*)p_wout_lo, bout, out);
}

// Round 4
// 2148.340 us; speedup vs baseline: 2.8400x; 2.8400x over previous
//
#include <hip/hip_runtime.h>

#define T_LEN   128
#define BATCH   32
#define SZ      512
#define VOCAB_N 32000
#define GATE3   1536   // 3*SZ
#define GBLK    64     // GRU blocks

typedef __attribute__((ext_vector_type(4))) float f32x4;
typedef __attribute__((ext_vector_type(8))) short bf16x8;
typedef __attribute__((ext_vector_type(4))) short s16x4;
typedef __attribute__((ext_vector_type(8))) short s16x8;

// ---------------- device scratch ----------------
__device__ short g_Wih_hi [GATE3 * SZ];
__device__ short g_Wih_lo [GATE3 * SZ];
__device__ short g_Wout_hi[VOCAB_N * SZ];
__device__ short g_Wout_lo[VOCAB_N * SZ];
__device__ short g_X_hi   [T_LEN * BATCH * SZ];
__device__ short g_X_lo   [T_LEN * BATCH * SZ];
__device__ short g_hs_hi  [T_LEN * BATCH * SZ];   // [t*32+b][s]
__device__ short g_hs_lo  [T_LEN * BATCH * SZ];
__device__ float g_giT    [GATE3 * T_LEN * BATCH]; // [gate-row n][t*32+b]
// h ring: slot t = 64KB: hi tile [32 rows(b) x 512 (s), swizzled] then lo tile
__device__ unsigned short g_ring[(T_LEN + 1) * 32768];
__device__ unsigned g_bar;

// ---------------- bf16 split helpers (manual RNE) ----------------
__device__ __forceinline__ unsigned short f2bf(float x) {
  unsigned int u = __float_as_uint(x);
  u += 0x7fffu + ((u >> 16) & 1u);
  return (unsigned short)(u >> 16);
}
__device__ __forceinline__ float bf2f(unsigned short h) {
  return __uint_as_float(((unsigned int)h) << 16);
}

// ---------------- tiny kernels ----------------
__global__ void zero_misc(float* __restrict__ p) {
  int i = blockIdx.x * 256 + threadIdx.x;
  if (i < BATCH * 10 * 10) p[i] = 0.f;
  if (i == 0) g_bar = 0u;
}

__global__ void split_f32(const float* __restrict__ src, short* __restrict__ hi,
                          short* __restrict__ lo, int n4) {
  int i = blockIdx.x * blockDim.x + threadIdx.x;
  int stride = gridDim.x * blockDim.x;
  for (; i < n4; i += stride) {
    f32x4 v = ((const f32x4*)src)[i];
    s16x4 h, l;
#pragma unroll
    for (int j = 0; j < 4; ++j) {
      unsigned short hb = f2bf(v[j]);
      h[j] = (short)hb;
      l[j] = (short)f2bf(v[j] - bf2f(hb));
    }
    ((s16x4*)hi)[i] = h;
    ((s16x4*)lo)[i] = l;
  }
}

__global__ void gather_split(const int* __restrict__ inp, const float* __restrict__ emb) {
  int i = blockIdx.x * 256 + threadIdx.x;      // [0, 4096*128)
  if (i >= T_LEN * BATCH * (SZ / 4)) return;
  int r  = i >> 7;
  int c  = (i & 127) * 4;
  int t  = r >> 5, b = r & 31;
  long idx = inp[b * T_LEN + t];
  f32x4 v = *(const f32x4*)&emb[idx * SZ + c];
  s16x4 h, l;
#pragma unroll
  for (int j = 0; j < 4; ++j) {
    unsigned short hb = f2bf(v[j]);
    h[j] = (short)hb;
    l[j] = (short)f2bf(v[j] - bf2f(hb));
  }
  *(s16x4*)&g_X_hi[(long)r * SZ + c] = h;
  *(s16x4*)&g_X_lo[(long)r * SZ + c] = l;
}

// ---------------- split-bf16 3-term MFMA GEMM ----------------
typedef const __attribute__((address_space(1))) short* gas_p;
typedef __attribute__((address_space(3))) short*       las_p;

__device__ __forceinline__ void gll16(const short* g, short* l) {
  __builtin_amdgcn_global_load_lds((gas_p)g, (las_p)l, 16, 0, 0);
}

// MODE 0: C[n*4096 + m]  transposed, f32x4 stores  (gi_T; bias = b_ih)
// MODE 1: C[(m&31)*T*V + (m>>5)*V + n]             (outputs; bias = b_out)
template <int MODE>
__global__ __launch_bounds__(256) void gemm3(
    const short* __restrict__ Ahi, const short* __restrict__ Alo,
    const short* __restrict__ Bhi, const short* __restrict__ Blo,
    const float* __restrict__ bias, float* __restrict__ C) {
  __shared__ __align__(16) short As[128 * 64];
  __shared__ __align__(16) short Bs[128 * 64];
  const int tid = threadIdx.x;

  // bijective XCD swizzle + 8-row supertile bands (gridDim.y % 8 == 0)
  const int gx  = gridDim.x;
  const int nwg = gx * gridDim.y;
  const int wg  = blockIdx.y * gx + blockIdx.x;
  const int cpx = nwg >> 3;
  const int swz = (wg & 7) * cpx + (wg >> 3);
  const int band = swz / (gx * 8);
  const int rr   = swz - band * (gx * 8);
  const long tileN = (long)(rr >> 3) * 128;
  const long tileM = (long)(band * 8 + (rr & 7)) * 128;

  const int wave = tid >> 6, lane = tid & 63;
  const int wm = (wave >> 1) * 64, wn = (wave & 1) * 64;
  const int lr = lane & 15, lk = lane >> 4;

  f32x4 acc[4][4] = {};

  for (int kt = 0; kt < 24; ++kt) {
    const int seg = kt >> 3;
    const int k0  = (kt & 7) * 64;
    const short* Asrc = (seg == 2) ? Alo : Ahi;
    const short* Bsrc = (seg == 1) ? Blo : Bhi;
#pragma unroll
    for (int i = 0; i < 4; ++i) {
      int elem = i * 2048 + tid * 8;
      int row  = elem >> 6, col = elem & 63;
      gll16(Asrc + (tileM + row) * SZ + k0 + col, As + elem);
      gll16(Bsrc + (tileN + row) * SZ + k0 + col, Bs + elem);
    }
    __syncthreads();
#pragma unroll
    for (int ks = 0; ks < 2; ++ks) {
      bf16x8 af[4], bfr[4];
#pragma unroll
      for (int f = 0; f < 4; ++f)
        af[f]  = *(const bf16x8*)&As[(wm + f * 16 + lr) * 64 + ks * 32 + lk * 8];
#pragma unroll
      for (int f = 0; f < 4; ++f)
        bfr[f] = *(const bf16x8*)&Bs[(wn + f * 16 + lr) * 64 + ks * 32 + lk * 8];
#pragma unroll
      for (int fm = 0; fm < 4; ++fm)
#pragma unroll
        for (int fn = 0; fn < 4; ++fn)
          acc[fm][fn] = __builtin_amdgcn_mfma_f32_16x16x32_bf16(
              af[fm], bfr[fn], acc[fm][fn], 0, 0, 0);
    }
    __syncthreads();
  }

#pragma unroll
  for (int fn = 0; fn < 4; ++fn) {
    const long n = tileN + wn + fn * 16 + lr;   // C/D: col = lane&15
    const float bi = bias[n];
#pragma unroll
    for (int fm = 0; fm < 4; ++fm) {
      const long m0 = tileM + wm + fm * 16 + lk * 4;  // row=(lane>>4)*4+r
      if (MODE == 0) {
        f32x4 v = acc[fm][fn];
        v[0] += bi; v[1] += bi; v[2] += bi; v[3] += bi;
        *(f32x4*)&C[n * (long)(T_LEN * BATCH) + m0] = v;
      } else {
#pragma unroll
        for (int r = 0; r < 4; ++r) {
          const long m = m0 + r;
          C[(m & 31) * (long)(T_LEN * VOCAB_N) + (m >> 5) * VOCAB_N + n] =
              acc[fm][fn][r] + bi;
        }
      }
    }
  }
}

// ---------------- rolled barrier (no L2 flush) ----------------
__device__ __forceinline__ void gbar(int tid, unsigned target) {
  __syncthreads();   // drains vmcnt (incl. sc1 stores) before arrive
  if (tid == 0) {
    __hip_atomic_fetch_add(&g_bar, 1u, __ATOMIC_RELAXED, __HIP_MEMORY_SCOPE_AGENT);
    int guard = 0;
    while (__hip_atomic_load(&g_bar, __ATOMIC_RELAXED, __HIP_MEMORY_SCOPE_AGENT)
               < target && guard < (1 << 18)) {
      ++guard;
      __builtin_amdgcn_s_sleep(1);
    }
  }
  __syncthreads();
  asm volatile("" ::: "memory");
}

// ---------------- GRU recurrence: per-step split-bf16 MFMA ----------------
// 64 blocks x 256 thr (cooperative). Block k owns s in [k*8, k*8+8).
// Per step: C[b=32][j=24] = h[32x512] . Wslice[24x512]^T via 3-term split-bf16
// MFMA (wave w -> Mtile=w&1, Ntile=w>>1). j = s_local*3 + gate.
// A (h bf16 hi/lo) staged from g_ring slot t via linear gll16; ring is stored
// PRE-SWIZZLED (byte ^ ((row&7)<<4) within 128B windows) so swizzled ds_reads
// are conflict-light. B (w_hh slice, pre-split) resident in LDS all steps.
__global__ __launch_bounds__(256) void gru_mfma(const float* __restrict__ lh,
                                                const float* __restrict__ whh,
                                                const float* __restrict__ bhh) {
  __shared__ __align__(16) short Ahl[32768];  // 64KB: hi[16384], lo[16384]
  __shared__ __align__(16) short Bhl[32768];  // 64KB: hi[16384], lo[16384]
  __shared__ float Cs[32 * 36];               // [col j][row b], pad 36
  const int tid  = threadIdx.x;
  const int blk  = blockIdx.x;
  const int lane = tid & 63;
  const int wave = tid >> 6;
  const int mt = wave & 1, nt = wave >> 1;
  const int s_local = tid >> 5;
  const int b  = tid & 31;
  const int s  = blk * 8 + s_local;

  // zero Bhl (pad rows must be defined), then fill 24 rows pre-split+swizzled
  {
    s16x8 zz = {};
#pragma unroll
    for (int i = 0; i < 16; ++i) *(s16x8*)&Bhl[(i * 256 + tid) * 8] = zz;
  }
  __syncthreads();
  for (int i = 0; i < 48; ++i) {
    int f = i * 256 + tid;            // [0, 12288)
    int j = f >> 9, k = f & 511;
    int sl = j / 3, gate = j - sl * 3;
    float w = whh[((long)(gate * SZ + blk * 8 + sl)) * SZ + k];
    unsigned short hb = f2bf(w);
    unsigned short lb = f2bf(w - bf2f(hb));
    int idx = j * 512 + (k & ~63) + ((k & 63) ^ ((j & 7) << 3));
    Bhl[idx] = (short)hb;
    Bhl[16384 + idx] = (short)lb;
  }

  // h0 for own (s,b); publish to ring slot 0 (swizzled position, sc1 stores)
  float h_self = lh[(s >> 8) * (BATCH * 256) + b * 256 + (s & 255)];
  const int idxA = b * 512 + (s & ~63) + ((s & 63) ^ ((b & 7) << 3));
  {
    unsigned short hb = f2bf(h_self);
    unsigned short lb = f2bf(h_self - bf2f(hb));
    __hip_atomic_store(&g_ring[idxA], hb, __ATOMIC_RELAXED, __HIP_MEMORY_SCOPE_AGENT);
    __hip_atomic_store(&g_ring[16384 + idxA], lb, __ATOMIC_RELAXED, __HIP_MEMORY_SCOPE_AGENT);
  }
  const float bhr = bhh[s];
  const float bhz = bhh[SZ + s];
  const float bhn = bhh[2 * SZ + s];
  __syncthreads();            // Bhl ready
  gbar(tid, GBLK * 1u);       // slot 0 globally visible

  for (int t = 0; t < T_LEN; ++t) {
    // stage ring slot t -> Ahl (linear 64KB copy; ring already swizzled)
    const unsigned short* src = &g_ring[(unsigned)t * 32768u];
#pragma unroll
    for (int i = 0; i < 16; ++i) {
      int e = (i * 256 + tid) * 8;
      gll16((const short*)src + e, Ahl + e);
    }
    __syncthreads();

    // MFMA: this wave computes C tile [mt*16..+16 rows(b)] x [nt*16..+16 cols(j)]
    f32x4 acc = {};
    const int arow = mt * 16 + (lane & 15);
    const int brow = nt * 16 + (lane & 15);
    const int asw = (arow & 7) << 3;
    const int bsw = (brow & 7) << 3;
#pragma unroll
    for (int kt = 0; kt < 16; ++kt) {
      const int k  = kt * 32 + (lane >> 4) * 8;
      const int ka = arow * 512 + (k & ~63) + ((k & 63) ^ asw);
      const int kb = brow * 512 + (k & ~63) + ((k & 63) ^ bsw);
      bf16x8 ah = *(const bf16x8*)&Ahl[ka];
      bf16x8 al = *(const bf16x8*)&Ahl[16384 + ka];
      bf16x8 bh = *(const bf16x8*)&Bhl[kb];
      bf16x8 bl = *(const bf16x8*)&Bhl[16384 + kb];
      acc = __builtin_amdgcn_mfma_f32_16x16x32_bf16(ah, bh, acc, 0, 0, 0);
      acc = __builtin_amdgcn_mfma_f32_16x16x32_bf16(ah, bl, acc, 0, 0, 0);
      acc = __builtin_amdgcn_mfma_f32_16x16x32_bf16(al, bh, acc, 0, 0, 0);
    }
    // C -> LDS scratch: Cs[col][row], row base = (lane>>4)*4 (+mt*16)
    {
      const int col = nt * 16 + (lane & 15);
      const int row = mt * 16 + (lane >> 4) * 4;
      *(f32x4*)&Cs[col * 36 + row] = acc;
    }
    __syncthreads();

    // epilogue: thread (s_local, b) assembles its gates
    const long mcol = (long)t * 32 + b;
    const float ar = Cs[(s_local * 3 + 0) * 36 + b];
    const float az = Cs[(s_local * 3 + 1) * 36 + b];
    const float an = Cs[(s_local * 3 + 2) * 36 + b];
    const float gir = g_giT[(long)(0 * SZ + s) * (T_LEN * BATCH) + mcol];
    const float giz = g_giT[(long)(SZ + s)     * (T_LEN * BATCH) + mcol];
    const float gin = g_giT[(long)(2 * SZ + s) * (T_LEN * BATCH) + mcol];
    const float rg = 1.f / (1.f + __expf(-(gir + ar + bhr)));
    const float zg = 1.f / (1.f + __expf(-(giz + az + bhz)));
    const float ng = tanhf(gin + rg * (an + bhn));
    const float hn = (1.f - zg) * ng + zg * h_self;
    h_self = hn;

    unsigned short hb = f2bf(hn);
    unsigned short lb = f2bf(hn - bf2f(hb));
    // hs in GEMM-A layout (plain stores; flushed at kernel end)
    g_hs_hi[mcol * SZ + s] = (short)hb;
    g_hs_lo[mcol * SZ + s] = (short)lb;
    // publish h_{t+1} into ring slot t+1 (sc1)
    __hip_atomic_store(&g_ring[(unsigned)(t + 1) * 32768u + idxA], hb,
                       __ATOMIC_RELAXED, __HIP_MEMORY_SCOPE_AGENT);
    __hip_atomic_store(&g_ring[(unsigned)(t + 1) * 32768u + 16384 + idxA], lb,
                       __ATOMIC_RELAXED, __HIP_MEMORY_SCOPE_AGENT);

    if (t < T_LEN - 1) gbar(tid, GBLK * (unsigned)(t + 2));
  }
}

// ---------------- host ----------------
extern "C" void kernel_launch(void* const* d_in, const int* in_sizes, int n_in,
                              void* d_out, int out_size, void* d_ws, size_t ws_size,
                              hipStream_t stream) {
  const int*   inp  = (const int*)  d_in[0];
  const float* lh   = (const float*)d_in[2];
  const float* emb  = (const float*)d_in[3];
  const float* wih  = (const float*)d_in[4];
  const float* whh  = (const float*)d_in[5];
  const float* bih  = (const float*)d_in[6];
  const float* bhh  = (const float*)d_in[7];
  const float* wout = (const float*)d_in[8];
  const float* bout = (const float*)d_in[9];
  float* out  = (float*)d_out;
  float* outw = out + (long)BATCH * T_LEN * VOCAB_N;

  void *p_wih_hi, *p_wih_lo, *p_wout_hi, *p_wout_lo, *p_x_hi, *p_x_lo,
       *p_hs_hi, *p_hs_lo, *p_giT;
  hipGetSymbolAddress(&p_wih_hi,  HIP_SYMBOL(g_Wih_hi));
  hipGetSymbolAddress(&p_wih_lo,  HIP_SYMBOL(g_Wih_lo));
  hipGetSymbolAddress(&p_wout_hi, HIP_SYMBOL(g_Wout_hi));
  hipGetSymbolAddress(&p_wout_lo, HIP_SYMBOL(g_Wout_lo));
  hipGetSymbolAddress(&p_x_hi,    HIP_SYMBOL(g_X_hi));
  hipGetSymbolAddress(&p_x_lo,    HIP_SYMBOL(g_X_lo));
  hipGetSymbolAddress(&p_hs_hi,   HIP_SYMBOL(g_hs_hi));
  hipGetSymbolAddress(&p_hs_lo,   HIP_SYMBOL(g_hs_lo));
  hipGetSymbolAddress(&p_giT,     HIP_SYMBOL(g_giT));

  // independent prep (also resets barrier counter every call)
  zero_misc<<<13, 256, 0, stream>>>(outw);
  split_f32<<<768, 256, 0, stream>>>(wih,  (short*)p_wih_hi,  (short*)p_wih_lo,
                                     GATE3 * SZ / 4);
  split_f32<<<2048, 256, 0, stream>>>(wout, (short*)p_wout_hi, (short*)p_wout_lo,
                                      VOCAB_N * SZ / 4);
  gather_split<<<2048, 256, 0, stream>>>(inp, emb);

  // gi_T = (X @ w_ih^T + b_ih)^T   [1536][4096]
  gemm3<0><<<dim3(GATE3 / 128, (T_LEN * BATCH) / 128), 256, 0, stream>>>(
      (const short*)p_x_hi, (const short*)p_x_lo,
      (const short*)p_wih_hi, (const short*)p_wih_lo, bih, (float*)p_giT);

  // GRU recurrence (cooperative for co-residency; barrier is ours)
  {
    void* args[3] = {(void*)&lh, (void*)&whh, (void*)&bhh};
    hipLaunchCooperativeKernel((void*)gru_mfma, dim3(GBLK), dim3(256), args, 0,
                               stream);
  }

  // outputs = hs @ w_out^T + b_out   -> [B, T, V]
  gemm3<1><<<dim3(VOCAB_N / 128, (T_LEN * BATCH) / 128), 256, 0, stream>>>(
      (const short*)p_hs_hi, (const short*)p_hs_lo,
      (const short*)p_wout_hi, (const short*)p_wout_lo, bout, out);
}